// Round 12
// baseline (208.098 us; speedup 1.0000x reference)
//
#include <hip/hip_runtime.h>
#include <math.h>

// ---------------- geometry ----------------
constexpr int N  = 167;          // field grid
constexpr int NN = 167 * 167;    // 27889
constexpr int NP = 90;           // input image
constexpr int MP = 84;           // pupil
constexpr int CROP = 120;
constexpr int HCOL = 84;         // Hermitian-reduced column count (t = 0..83)
constexpr int HALF_SZ = 1784896; // (16*167*167*8)/2  for threefry pairing

// ---------------- ws arena (float offsets) ----------------
constexpr size_t SZ_MAT   = (size_t)NN * 2;
constexpr size_t OFF_M1   = 0;
constexpr size_t OFF_M1T  = OFF_M1 + SZ_MAT;
constexpr size_t OFF_WF   = OFF_M1T + SZ_MAT;
constexpr size_t OFF_M2   = OFF_WF + SZ_MAT;
constexpr size_t OFF_M2T  = OFF_M2 + SZ_MAT;
constexpr size_t OFF_M3   = OFF_M2T + SZ_MAT;                  // [120][167] c
constexpr size_t OFF_M3T84= OFF_M3 + (size_t)CROP * N * 2;     // [84][120] c
constexpr size_t OFF_PHI2 = OFF_M3T84 + (size_t)HCOL * CROP * 2; // [167] c
constexpr size_t OFF_AMP  = OFF_PHI2 + (size_t)N * 2;
constexpr size_t OFF_X    = OFF_AMP + 2;                       // [16][167][84] c
constexpr size_t OFF_T1   = OFF_X  + (size_t)16 * N * HCOL * 2;// [16][167][90] c
constexpr size_t OFF_A    = OFF_T1 + (size_t)16 * N * NP * 2;  // [16][167][167] c
constexpr size_t OFF_T2   = OFF_A  + (size_t)16 * NN * 2;      // [16][167][84] c
constexpr size_t OFF_BD   = OFF_T2 + (size_t)16 * N * MP * 2;  // (unused now)
constexpr size_t OFF_T3   = OFF_BD + (size_t)8 * NN;           // [8][167][84] c
constexpr size_t OFF_OTF  = OFF_T3 + (size_t)8 * N * HCOL * 2; // [8][167][84] c
constexpr size_t OFF_FLAT = OFF_OTF+ (size_t)8 * N * HCOL * 2; // [16][12800]
constexpr size_t OFF_PC   = OFF_FLAT + (size_t)16 * 12800;     // [16][84][84] c
constexpr size_t WS_FLOATS = OFF_PC + (size_t)16 * MP * MP * 2;

// ---------------- helpers ----------------
__device__ __forceinline__ unsigned rotl32(unsigned x, int r) {
    return (x << r) | (x >> (32 - r));
}

// jax.random.normal(key(42), [16,167,167,8]) element at flat index idx
__device__ float noise_at(unsigned idx) {
    unsigned c0, c1; int lane;
    if (idx < (unsigned)HALF_SZ) { c0 = idx; c1 = idx + HALF_SZ; lane = 0; }
    else                         { c0 = idx - HALF_SZ; c1 = idx; lane = 1; }
    const unsigned ks0 = 0u, ks1 = 42u, ks2 = 0x1BD11BDAu ^ 42u;
    unsigned x0 = c0 + ks0, x1 = c1 + ks1;
#define TFR(r) { x0 += x1; x1 = rotl32(x1, r); x1 ^= x0; }
    TFR(13) TFR(15) TFR(26) TFR(6)   x0 += ks1; x1 += ks2 + 1u;
    TFR(17) TFR(29) TFR(16) TFR(24)  x0 += ks2; x1 += ks0 + 2u;
    TFR(13) TFR(15) TFR(26) TFR(6)   x0 += ks0; x1 += ks1 + 3u;
    TFR(17) TFR(29) TFR(16) TFR(24)  x0 += ks1; x1 += ks2 + 4u;
    TFR(13) TFR(15) TFR(26) TFR(6)   x0 += ks2; x1 += ks0 + 5u;
#undef TFR
    unsigned bits = lane ? x1 : x0;
    float u01 = __uint_as_float((bits >> 9) | 0x3F800000u) - 1.0f;
    const float lo = -0.99999994f;
    float f = fmaxf(lo, u01 * 2.0f + lo);
    float w = -log1pf(-f * f);
    float p;
    if (w < 5.0f) {
        w -= 2.5f;
        p = 2.81022636e-08f;
        p = fmaf(p, w, 3.43273939e-07f);
        p = fmaf(p, w, -3.5233877e-06f);
        p = fmaf(p, w, -4.39150654e-06f);
        p = fmaf(p, w, 0.00021858087f);
        p = fmaf(p, w, -0.00125372503f);
        p = fmaf(p, w, -0.00417768164f);
        p = fmaf(p, w, 0.246640727f);
        p = fmaf(p, w, 1.50140941f);
    } else {
        w = sqrtf(w) - 3.0f;
        p = -0.000200214257f;
        p = fmaf(p, w, 0.000100950558f);
        p = fmaf(p, w, 0.00134934322f);
        p = fmaf(p, w, -0.00367342844f);
        p = fmaf(p, w, 0.00573950773f);
        p = fmaf(p, w, -0.0076224613f);
        p = fmaf(p, w, 0.00943887047f);
        p = fmaf(p, w, 1.00167406f);
        p = fmaf(p, w, 2.83297682f);
    }
    return 1.41421356237f * p * f;
}

// ---------------- prep: DFT matrices (via omega table) + pupil field + disk area ----------------
__global__ void k_prep(const float* __restrict__ P, float* ws) {
    int bx = blockIdx.x, t = threadIdx.x;
    if (bx < 109) {
        __shared__ float2 wtab[N];   // wtab[s] = exp(+2pi i s/167) as (cos, sin)
        const float TPI = (float)(6.283185307179586476925286766559 / 167.0);
        for (int i = t; i < N; i += 256) {
            float s, c; sincosf(TPI * (float)i, &s, &c);
            wtab[i] = make_float2(c, s);
        }
        __syncthreads();
        int id = bx * 256 + t;
        if (id >= NN) return;
        int k = id / N, m = id % N;
        const float inv = 1.0f / 167.0f;
        int t1 = ((k + 84) * ((m + 83) % N)) % N;
        float2 w1 = wtab[t1];
        ws[OFF_M1 + 2 * id] = w1.x;  ws[OFF_M1 + 2 * id + 1] = -w1.y;
        ws[OFF_M1T + 2 * (m * N + k)] = w1.x;  ws[OFF_M1T + 2 * (m * N + k) + 1] = -w1.y;
        int tw = (k * m) % N;
        float2 ww = wtab[tw];
        ws[OFF_WF + 2 * id] = ww.x;  ws[OFF_WF + 2 * id + 1] = -ww.y;
        int t2 = ((k + 84) * m) % N;
        float2 w2 = wtab[t2];
        ws[OFF_M2 + 2 * id] = w2.x * inv;  ws[OFF_M2 + 2 * id + 1] = w2.y * inv;
        ws[OFF_M2T + 2 * (m * N + k)] = w2.x * inv;  ws[OFF_M2T + 2 * (m * N + k) + 1] = w2.y * inv;
        if (k < CROP) {
            int t3 = ((k + 108) * ((m + 83) % N)) % N;
            float2 w3 = wtab[t3];
            ws[OFF_M3 + 2 * (k * N + m)] = w3.x * inv;  ws[OFF_M3 + 2 * (k * N + m) + 1] = w3.y * inv;
            if (m < HCOL) {
                ws[OFF_M3T84 + 2 * (m * CROP + k)] = w3.x * inv;
                ws[OFF_M3T84 + 2 * (m * CROP + k) + 1] = w3.y * inv;
            }
        }
        if (id < N) {
            float2 wp = wtab[(2 * id) % N];
            ws[OFF_PHI2 + 2 * id] = wp.x;
            ws[OFF_PHI2 + 2 * id + 1] = wp.y;
        }
    } else if (bx < 550) {
        int id = (bx - 109) * 256 + t;
        if (id >= 16 * MP * MP) return;
        int rc = id % (MP * MP);
        int r = rc / MP, c = rc % MP;
        float y = r - 41.5f, x = c - 41.5f;
        float2 v = {0.f, 0.f};
        if (x * x + y * y <= 1764.0f) {
            float sp, cp; sincosf(P[id], &sp, &cp);
            v.x = cp; v.y = sp;
        }
        ((float2*)(ws + OFF_PC))[id] = v;
    } else {
        __shared__ int red[256];
        int cnt = 0;
        for (int i = t; i < MP * MP; i += 256) {
            int r = i / MP, c = i % MP;
            float y = r - 41.5f, x = c - 41.5f;
            if (x * x + y * y <= 1764.0f) cnt++;
        }
        red[t] = cnt; __syncthreads();
        for (int s = 128; s > 0; s >>= 1) { if (t < s) red[t] += red[t + s]; __syncthreads(); }
        if (t == 0) ws[OFF_AMP] = (float)red[0];
    }
}

// ---------------- row transforms: T1 = M1 * xpad  |  T2 = F * Pc ----------------
__global__ __launch_bounds__(128) void k_rows(const float* __restrict__ x, float* ws) {
    int kr = blockIdx.x, bj = blockIdx.y, t = threadIdx.x;
    __shared__ float2 wbuf[NP];
    if (blockIdx.z == 0) {
        const float2* M1 = (const float2*)(ws + OFF_M1);
        if (t < NP) wbuf[t] = M1[kr * N + 39 + t];
        __syncthreads();
        if (t >= NP) return;
        float2 acc = {0.f, 0.f};
        for (int nr = 0; nr < NP; nr++) {
            float2 w = wbuf[nr];
            float xv = x[(bj * NP + nr) * NP + t];
            acc.x += w.x * xv; acc.y += w.y * xv;
        }
        ((float2*)(ws + OFF_T1))[(bj * N + kr) * NP + t] = acc;
    } else {
        const float2* WF = (const float2*)(ws + OFF_WF);
        if (t < MP) wbuf[t] = WF[kr * N + 42 + t];
        __syncthreads();
        if (t >= MP) return;
        const float2* PC = (const float2*)(ws + OFF_PC) + (size_t)bj * MP * MP;
        float2 acc = {0.f, 0.f};
        for (int nr = 0; nr < MP; nr++) {
            float2 w = wbuf[nr];
            float2 pc = PC[nr * MP + t];
            acc.x += w.x * pc.x - w.y * pc.y;
            acc.y += w.x * pc.y + w.y * pc.x;
        }
        ((float2*)(ws + OFF_T2))[(bj * N + kr) * MP + t] = acc;
    }
}

// ---------------- col transforms: X (Hermitian-halved) | A (full) ----------------
constexpr int RCH = 6;
__global__ __launch_bounds__(192) void k_cols(float* ws) {
    int bj = blockIdx.y, tid = threadIdx.x;
    __shared__ float2 sbuf[RCH * MP];   // 504 float2, covers both uses
    if (blockIdx.x < 84) {
        // ---- X[:,0..83] = T1 * M1^T, 2 rows/block ----
        int k0 = blockIdx.x * 2;
        const float2* T1 = (const float2*)(ws + OFF_T1);
        for (int idx = tid; idx < 2 * NP; idx += 192) {
            int r = idx / NP, m = idx % NP;
            if (k0 + r < N) sbuf[r * NP + m] = T1[((size_t)bj * N + k0 + r) * NP + m];
        }
        __syncthreads();
        int col = tid % HCOL, grp = tid / HCOL;
        if (grp >= 2) return;
        int kr = k0 + grp;
        if (kr >= N) return;
        const float2* M1T = (const float2*)(ws + OFF_M1T);
        float2 acc = {0.f, 0.f};
        for (int nc = 0; nc < NP; nc++) {
            float2 u = sbuf[grp * NP + nc];
            float2 w = M1T[(39 + nc) * N + col];
            acc.x += u.x * w.x - u.y * w.y;
            acc.y += u.x * w.y + u.y * w.x;
        }
        ((float2*)(ws + OFF_X))[((size_t)bj * N + kr) * HCOL + col] = acc;
    } else {
        // ---- A = T2 * F^T, 6 rows/block, full 167 cols ----
        int i0 = (blockIdx.x - 84) * RCH;
        const float2* T2 = (const float2*)(ws + OFF_T2);
        for (int idx = tid; idx < RCH * MP; idx += 192) {
            int q = idx / MP, nc = idx % MP, kr = i0 + q;
            if (kr < N) sbuf[idx] = T2[(bj * N + kr) * MP + nc];
        }
        __syncthreads();
        if (tid >= N) return;
        const float2* WF = (const float2*)(ws + OFF_WF);
        float2 acc[RCH];
#pragma unroll
        for (int q = 0; q < RCH; q++) acc[q] = make_float2(0.f, 0.f);
        for (int nc = 0; nc < MP; nc++) {
            float2 w = WF[(42 + nc) * N + tid];
#pragma unroll
            for (int q = 0; q < RCH; q++) {
                float2 u = sbuf[q * MP + nc];
                acc[q].x += u.x * w.x - u.y * w.y;
                acc[q].y += u.x * w.y + u.y * w.x;
            }
        }
        float2* A = (float2*)(ws + OFF_A);
#pragma unroll
        for (int q = 0; q < RCH; q++)
            if (i0 + q < N) A[((size_t)bj * N + i0 + q) * N + tid] = acc[q];
    }
}

// ---------------- stage 2c: T3[k, 0..83] = sum_m Bd[k,m] * M2T[m,t], Bd inline ----------------
__global__ __launch_bounds__(192) void k2c(float* ws) {
    int chunk = blockIdx.x, c = blockIdx.y, tid = threadIdx.x;
    int k0 = chunk * 2;
    __shared__ float bds[2][N];
    const float2* A = (const float2*)(ws + OFF_A);
    float inv_amp = 1.0f / ws[OFF_AMP];
    for (int idx = tid; idx < 2 * N; idx += 192) {
        int r = idx / N, m = idx % N;
        int k = k0 + r;
        if (k < N) {
            float2 a0 = A[((size_t)c * N + k) * N + m];
            float2 a1 = A[((size_t)(c + 8) * N + k) * N + m];
            bds[r][m] = (a0.x * a0.x + a0.y * a0.y - a1.x * a1.x - a1.y * a1.y) * inv_amp;
        }
    }
    __syncthreads();
    int col = tid % HCOL, grp = tid / HCOL;
    if (grp >= 2) return;
    int k = k0 + grp;
    if (k >= N) return;
    const float2* M2T = (const float2*)(ws + OFF_M2T);
    float2 acc = {0.f, 0.f};
    for (int m = 0; m < N; m++) {
        float bv = bds[grp][m];
        float2 w = M2T[m * N + col];
        acc.x += w.x * bv; acc.y += w.y * bv;
    }
    ((float2*)(ws + OFF_T3))[((size_t)c * N + k) * HCOL + col] = acc;
}

// ---------------- stage 2d: OTF[i, 0..83] = sum_k M2[i,k] * T3[k,t] ----------------
__global__ __launch_bounds__(192) void k2d(float* ws) {
    int chunk = blockIdx.x, c = blockIdx.y, tid = threadIdx.x;
    int i0 = chunk * 2;
    __shared__ float2 m2s[2][N];
    const float2* M2 = (const float2*)(ws + OFF_M2);
    for (int idx = tid; idx < 2 * N; idx += 192) {
        int r = idx / N, k = idx % N;
        if (i0 + r < N) m2s[r][k] = M2[(i0 + r) * N + k];
    }
    __syncthreads();
    int col = tid % HCOL, grp = tid / HCOL;
    if (grp >= 2) return;
    int i = i0 + grp;
    if (i >= N) return;
    const float2* T3 = (const float2*)(ws + OFF_T3) + (size_t)c * N * HCOL;
    float2 acc = {0.f, 0.f};
    for (int k = 0; k < N; k++) {
        float2 w = m2s[grp][k];
        float2 u = T3[k * HCOL + col];
        acc.x += u.x * w.x - u.y * w.y;
        acc.y += u.x * w.y + u.y * w.x;
    }
    ((float2*)(ws + OFF_OTF))[((size_t)c * N + i) * HCOL + col] = acc;
}

// ---------------- stage 3 fused: 12 rows/block, DOUBLE-BUFFERED (1 barrier/chunk),
//                  us aliased onto zs (dead after phase 1) ----------------
constexpr int K34R = 12;   // rows per block (4 pool rows)
constexpr int KCH  = 16;   // kr chunk staged per iteration
constexpr int NT34 = (N + KCH - 1) / KCH;   // 11 (10 full + 1 tail of 7)

// LDS layout (floats):
//   zs  : [2][KCH][HCOL] float2  @ 0       (21504 B)  -- aliased by us[K34R][HCOL] after loop
//   m3c : [2][KCH][K34R] float2  @ 5376    (3072 B)
//   phis: [N] float2             @ 6144    (1336 B)
//   pm  : [4][CROP] float        @ 6478    (1920 B)
constexpr int SM_ZS   = 0;
constexpr int SM_M3C  = SM_ZS + 2 * KCH * HCOL * 2;      // 5376
constexpr int SM_PHIS = SM_M3C + 2 * KCH * K34R * 2;     // 6144
constexpr int SM_PM   = SM_PHIS + N * 2;                 // 6478
constexpr int SM_TOT  = SM_PM + 4 * CROP;                // 6958 floats = 27832 B

constexpr int ZBUF = KCH * HCOL;    // float2 elements per zs buffer
constexpr int MBUF = KCH * K34R;    // float2 elements per m3c buffer

#define K34_FMA_BODY(kl)                                                        \
    {                                                                           \
        float4 zz = *(const float4*)&zcur[(kl) * HCOL + 2 * pair];              \
        float4 wa = *(const float4*)&mcur[(kl) * K34R + r0];                    \
        a00.x += wa.x * zz.x - wa.y * zz.y;  a00.y += wa.x * zz.y + wa.y * zz.x;\
        a01.x += wa.x * zz.z - wa.y * zz.w;  a01.y += wa.x * zz.w + wa.y * zz.z;\
        a10.x += wa.z * zz.x - wa.w * zz.y;  a10.y += wa.z * zz.y + wa.w * zz.x;\
        a11.x += wa.z * zz.z - wa.w * zz.w;  a11.y += wa.z * zz.w + wa.w * zz.z;\
    }

__global__ __launch_bounds__(256) void k34(float* ws) {
    int chunk = blockIdx.x, c = blockIdx.y, b = blockIdx.z, tid = threadIdx.x;
    int i0 = chunk * K34R;
    __shared__ __align__(16) float smem[SM_TOT];
    float2* zbase = (float2*)(smem + SM_ZS);
    float2* mbase = (float2*)(smem + SM_M3C);
    float2* phis  = (float2*)(smem + SM_PHIS);
    float*  pmf   = smem + SM_PM;                            // pm[4][CROP] flat
    float2 (*us)[HCOL] = (float2 (*)[HCOL])(smem + SM_ZS);   // alias: zs dead after loop

    const float2* M3  = (const float2*)(ws + OFF_M3);
    const float2* X   = (const float2*)(ws + OFF_X)   + (size_t)b * N * HCOL;
    const float2* OTF = (const float2*)(ws + OFF_OTF) + (size_t)c * N * HCOL;
    for (int idx = tid; idx < N; idx += 256) phis[idx] = ((const float2*)(ws + OFF_PHI2))[idx];

    // staging coordinates for zs (6 elements/thread, computed once)
    int skl[6], scol[6];
#pragma unroll
    for (int e = 0; e < 6; e++) {
        int idx = tid + e * 256;
        skl[e] = idx / HCOL; scol[e] = idx - skl[e] * HCOL;   // skl<16 valid
    }
    // staging coordinates for m3c (1 element/thread, tid<192): coalesced over kl
    int mkl = tid & 15, mr = tid >> 4;   // tid<192: kl 0..15, r 0..11

    int pair = tid % 42, grp = tid / 42;   // grp<6: 2 rows x 2 cols per thread
    int r0 = grp * 2;
    float2 a00 = {0.f,0.f}, a01 = {0.f,0.f}, a10 = {0.f,0.f}, a11 = {0.f,0.f};

    float2 xr[6], og[6], m3r;

    // ---- prologue: load chunk 0 to regs, write LDS buf 0 ----
#pragma unroll
    for (int e = 0; e < 6; e++)
        if (skl[e] < KCH) { xr[e] = X[skl[e] * HCOL + scol[e]]; og[e] = OTF[skl[e] * HCOL + scol[e]]; }
    if (tid < 192) m3r = M3[(i0 + mr) * N + mkl];
#pragma unroll
    for (int e = 0; e < 6; e++)
        if (skl[e] < KCH)
            zbase[skl[e] * HCOL + scol[e]] = make_float2(xr[e].x * og[e].x - xr[e].y * og[e].y,
                                                         xr[e].x * og[e].y + xr[e].y * og[e].x);
    if (tid < 192) mbase[mkl * K34R + mr] = m3r;
    __syncthreads();

    // ---- main loop: prefetch(t+1) -> FMA(t) on cbuf (writes to nbuf interleave) -> barrier ----
    for (int t = 0; t < NT34; t++) {
        int cbuf = t & 1, nbuf = cbuf ^ 1;
        int kr0 = t * KCH;
        int chn = min(KCH, N - kr0);
        int nbase = kr0 + KCH;
        int nchn = (t + 1 < NT34) ? (N - nbase < KCH ? N - nbase : KCH) : 0;
        if (nchn > 0) {
#pragma unroll
            for (int e = 0; e < 6; e++)
                if (skl[e] < nchn) { xr[e] = X[(nbase + skl[e]) * HCOL + scol[e]];
                                     og[e] = OTF[(nbase + skl[e]) * HCOL + scol[e]]; }
            if (tid < 192 && mkl < nchn) m3r = M3[(i0 + mr) * N + nbase + mkl];
        }
        const float2* zcur = zbase + cbuf * ZBUF;
        const float2* mcur = mbase + cbuf * MBUF;
        if (grp < 6) {
            if (chn == KCH) {
#pragma unroll
                for (int kl = 0; kl < KCH; kl++) K34_FMA_BODY(kl)
            } else {
#pragma unroll
                for (int kl = 0; kl < KCH - 9; kl++) K34_FMA_BODY(kl)   // tail chn = 7
            }
        }
        // write next chunk into the OTHER buffer: no barrier needed before these,
        // they interleave with the FMA stream above (different LDS region)
        if (nchn > 0) {
            float2* znxt = zbase + nbuf * ZBUF;
            float2* mnxt = mbase + nbuf * MBUF;
#pragma unroll
            for (int e = 0; e < 6; e++)
                if (skl[e] < nchn)
                    znxt[skl[e] * HCOL + scol[e]] = make_float2(xr[e].x * og[e].x - xr[e].y * og[e].y,
                                                                xr[e].x * og[e].y + xr[e].y * og[e].x);
            if (tid < 192 && mkl < nchn) mnxt[mkl * K34R + mr] = m3r;
        }
        __syncthreads();
    }

    // ---- write U rows (us aliases zs; all zs reads completed before last barrier) ----
    if (grp < 6) {
        *(float4*)&us[r0][2 * pair]     = make_float4(a00.x, a00.y, a01.x, a01.y);
        *(float4*)&us[r0 + 1][2 * pair] = make_float4(a10.x, a10.y, a11.x, a11.y);
    }
    __syncthreads();

    // ---- phase 2: j-transform + phase fixup + noise + relu + 3-row max ----
    if (tid < 240) {
        int grp2 = tid / CROP, j = tid % CROP;
        int rbase = grp2 * 6;
        const float2* M3T84 = (const float2*)(ws + OFF_M3T84);
        float2 A[6]; float Bq[6];
#pragma unroll
        for (int q = 0; q < 6; q++) A[q] = make_float2(0.f, 0.f);
        // nc pairs (0,1)..(80,81): one float4 us read covers both nc of a row
#pragma unroll 4
        for (int ncp = 0; ncp < 41; ncp++) {
            int nc = 2 * ncp;
            float2 w0 = M3T84[nc * CROP + j];
            float2 w1 = M3T84[(nc + 1) * CROP + j];
#pragma unroll
            for (int q = 0; q < 6; q++) {
                float4 u = *(const float4*)&us[rbase + q][nc];
                A[q].x += u.x * w0.x - u.y * w0.y;
                A[q].y += u.x * w0.y + u.y * w0.x;
                A[q].x += u.z * w1.x - u.w * w1.y;
                A[q].y += u.z * w1.y + u.w * w1.x;
            }
        }
        {   // nc = 82 singleton
            float2 w = M3T84[82 * CROP + j];
#pragma unroll
            for (int q = 0; q < 6; q++) {
                float2 u = us[rbase + q][82];
                A[q].x += u.x * w.x - u.y * w.y;
                A[q].y += u.x * w.y + u.y * w.x;
            }
        }
        {   // B term: nc = 83 (self-paired column), real part only
            float2 w = M3T84[(HCOL - 1) * CROP + j];
#pragma unroll
            for (int q = 0; q < 6; q++) {
                float2 u = us[rbase + q][HCOL - 1];
                Bq[q] = u.x * w.x - u.y * w.y;
            }
        }
#pragma unroll
        for (int g = 0; g < 2; g++) {
            float vmax = 0.f;  // relu folded in
#pragma unroll
            for (int r = 0; r < 3; r++) {
                int q = g * 3 + r, i = i0 + rbase + q;
                int s = i + j + 49; if (s >= N) s -= N;   // (i+j+216) mod 167
                float2 ph = phis[s];
                float val = A[q].x * (1.0f + ph.x) - A[q].y * ph.y + Bq[q];
                unsigned idx = (((unsigned)b * N + (24 + i)) * N + (24 + j)) * 8u + c;
                val += 0.003f * noise_at(idx);
                vmax = fmaxf(vmax, val);
            }
            pmf[(grp2 * 2 + g) * CROP + j] = vmax;
        }
    }
    __syncthreads();
    if (tid < 160) {
        int pr = tid / 40, pc = tid % 40;
        float m = fmaxf(fmaxf(pmf[pr * CROP + 3 * pc], pmf[pr * CROP + 3 * pc + 1]),
                        pmf[pr * CROP + 3 * pc + 2]);
        int prow = chunk * 4 + pr;
        ws[OFF_FLAT + (size_t)b * 12800 + ((size_t)prow * 40 + pc) * 8 + c] = m;
    }
}

// ---------------- stage 4: dense(12800->10) + softmax ----------------
__global__ void k5(const float* __restrict__ W3, const float* __restrict__ b3,
                   const float* __restrict__ ws, float* __restrict__ out) {
    int b = blockIdx.x, t = threadIdx.x;
    __shared__ float red[256][10];
    float acc[10];
#pragma unroll
    for (int o = 0; o < 10; o++) acc[o] = 0.f;
    const float* fl = ws + OFF_FLAT + (size_t)b * 12800;
    for (int f = t; f < 12800; f += 256) {
        float v = fl[f];
#pragma unroll
        for (int o = 0; o < 10; o++) acc[o] = fmaf(v, W3[f * 10 + o], acc[o]);
    }
#pragma unroll
    for (int o = 0; o < 10; o++) red[t][o] = acc[o];
    __syncthreads();
    for (int s = 128; s > 0; s >>= 1) {
        if (t < s) {
#pragma unroll
            for (int o = 0; o < 10; o++) red[t][o] += red[t + s][o];
        }
        __syncthreads();
    }
    if (t == 0) {
        float lg[10], mx = -1e30f;
#pragma unroll
        for (int o = 0; o < 10; o++) { lg[o] = red[0][o] + b3[o]; mx = fmaxf(mx, lg[o]); }
        float sum = 0.f;
#pragma unroll
        for (int o = 0; o < 10; o++) { lg[o] = expf(lg[o] - mx); sum += lg[o]; }
#pragma unroll
        for (int o = 0; o < 10; o++) out[b * 10 + o] = lg[o] / sum;
    }
}

extern "C" void kernel_launch(void* const* d_in, const int* in_sizes, int n_in,
                              void* d_out, int out_size, void* d_ws, size_t ws_size,
                              hipStream_t stream) {
    const float* x  = (const float*)d_in[0];   // [16,90,90,1]
    const float* P  = (const float*)d_in[1];   // [16,84,84]
    const float* W3 = (const float*)d_in[2];   // [12800,10]
    const float* b3 = (const float*)d_in[3];   // [10]
    float* ws  = (float*)d_ws;
    float* out = (float*)d_out;                // [16,10]

    k_prep<<<551, 256, 0, stream>>>(P, ws);
    k_rows<<<dim3(N, 16, 2), 128, 0, stream>>>(x, ws);
    k_cols<<<dim3(84 + 28, 16), 192, 0, stream>>>(ws);
    k2c<<<dim3(84, 8), 192, 0, stream>>>(ws);
    k2d<<<dim3(84, 8), 192, 0, stream>>>(ws);
    k34<<<dim3(CROP / K34R, 8, 16), 256, 0, stream>>>(ws);
    k5<<<16, 256, 0, stream>>>(W3, b3, ws, out);
}

// Round 13
// 204.338 us; speedup vs baseline: 1.0184x; 1.0184x over previous
//
#include <hip/hip_runtime.h>
#include <math.h>

// ---------------- geometry ----------------
constexpr int N  = 167;          // field grid
constexpr int NN = 167 * 167;    // 27889
constexpr int NP = 90;           // input image
constexpr int MP = 84;           // pupil
constexpr int CROP = 120;
constexpr int HCOL = 84;         // Hermitian-reduced column count (t = 0..83)
constexpr int HALF_SZ = 1784896; // (16*167*167*8)/2  for threefry pairing

// ---------------- ws arena (float offsets) ----------------
constexpr size_t SZ_MAT   = (size_t)NN * 2;
constexpr size_t OFF_M1   = 0;
constexpr size_t OFF_M1T  = OFF_M1 + SZ_MAT;
constexpr size_t OFF_WF   = OFF_M1T + SZ_MAT;
constexpr size_t OFF_M2   = OFF_WF + SZ_MAT;
constexpr size_t OFF_M2T  = OFF_M2 + SZ_MAT;
constexpr size_t OFF_M3   = OFF_M2T + SZ_MAT;                  // [120][167] c
constexpr size_t OFF_M3T84= OFF_M3 + (size_t)CROP * N * 2;     // [84][120] c
constexpr size_t OFF_PHI2 = OFF_M3T84 + (size_t)HCOL * CROP * 2; // [167] c
constexpr size_t OFF_AMP  = OFF_PHI2 + (size_t)N * 2;
constexpr size_t OFF_X    = OFF_AMP + 4;                       // [16][167][84] c (16B-aligned)
constexpr size_t OFF_T1   = OFF_X  + (size_t)16 * N * HCOL * 2;// [16][167][90] c
constexpr size_t OFF_A    = OFF_T1 + (size_t)16 * N * NP * 2;  // [16][167][167] c
constexpr size_t OFF_T2   = OFF_A  + (size_t)16 * NN * 2;      // [16][167][84] c
constexpr size_t OFF_BD   = OFF_T2 + (size_t)16 * N * MP * 2;  // (unused now)
constexpr size_t OFF_T3   = OFF_BD + (size_t)8 * NN;           // [8][167][84] c
constexpr size_t OFF_OTF  = OFF_T3 + (size_t)8 * N * HCOL * 2; // [8][167][84] c
constexpr size_t OFF_FLAT = OFF_OTF+ (size_t)8 * N * HCOL * 2; // [16][12800]
constexpr size_t OFF_PC   = OFF_FLAT + (size_t)16 * 12800;     // [16][84][84] c
constexpr size_t WS_FLOATS = OFF_PC + (size_t)16 * MP * MP * 2;

// ---------------- helpers ----------------
__device__ __forceinline__ unsigned rotl32(unsigned x, int r) {
    return (x << r) | (x >> (32 - r));
}

// jax.random.normal(key(42), [16,167,167,8]) element at flat index idx
__device__ float noise_at(unsigned idx) {
    unsigned c0, c1; int lane;
    if (idx < (unsigned)HALF_SZ) { c0 = idx; c1 = idx + HALF_SZ; lane = 0; }
    else                         { c0 = idx - HALF_SZ; c1 = idx; lane = 1; }
    const unsigned ks0 = 0u, ks1 = 42u, ks2 = 0x1BD11BDAu ^ 42u;
    unsigned x0 = c0 + ks0, x1 = c1 + ks1;
#define TFR(r) { x0 += x1; x1 = rotl32(x1, r); x1 ^= x0; }
    TFR(13) TFR(15) TFR(26) TFR(6)   x0 += ks1; x1 += ks2 + 1u;
    TFR(17) TFR(29) TFR(16) TFR(24)  x0 += ks2; x1 += ks0 + 2u;
    TFR(13) TFR(15) TFR(26) TFR(6)   x0 += ks0; x1 += ks1 + 3u;
    TFR(17) TFR(29) TFR(16) TFR(24)  x0 += ks1; x1 += ks2 + 4u;
    TFR(13) TFR(15) TFR(26) TFR(6)   x0 += ks2; x1 += ks0 + 5u;
#undef TFR
    unsigned bits = lane ? x1 : x0;
    float u01 = __uint_as_float((bits >> 9) | 0x3F800000u) - 1.0f;
    const float lo = -0.99999994f;
    float f = fmaxf(lo, u01 * 2.0f + lo);
    float w = -log1pf(-f * f);
    float p;
    if (w < 5.0f) {
        w -= 2.5f;
        p = 2.81022636e-08f;
        p = fmaf(p, w, 3.43273939e-07f);
        p = fmaf(p, w, -3.5233877e-06f);
        p = fmaf(p, w, -4.39150654e-06f);
        p = fmaf(p, w, 0.00021858087f);
        p = fmaf(p, w, -0.00125372503f);
        p = fmaf(p, w, -0.00417768164f);
        p = fmaf(p, w, 0.246640727f);
        p = fmaf(p, w, 1.50140941f);
    } else {
        w = sqrtf(w) - 3.0f;
        p = -0.000200214257f;
        p = fmaf(p, w, 0.000100950558f);
        p = fmaf(p, w, 0.00134934322f);
        p = fmaf(p, w, -0.00367342844f);
        p = fmaf(p, w, 0.00573950773f);
        p = fmaf(p, w, -0.0076224613f);
        p = fmaf(p, w, 0.00943887047f);
        p = fmaf(p, w, 1.00167406f);
        p = fmaf(p, w, 2.83297682f);
    }
    return 1.41421356237f * p * f;
}

// ---------------- prep: DFT matrices (via omega table) + pupil field + disk area ----------------
__global__ void k_prep(const float* __restrict__ P, float* ws) {
    int bx = blockIdx.x, t = threadIdx.x;
    if (bx < 109) {
        __shared__ float2 wtab[N];   // wtab[s] = exp(+2pi i s/167) as (cos, sin)
        const float TPI = (float)(6.283185307179586476925286766559 / 167.0);
        for (int i = t; i < N; i += 256) {
            float s, c; sincosf(TPI * (float)i, &s, &c);
            wtab[i] = make_float2(c, s);
        }
        __syncthreads();
        int id = bx * 256 + t;
        if (id >= NN) return;
        int k = id / N, m = id % N;
        const float inv = 1.0f / 167.0f;
        int t1 = ((k + 84) * ((m + 83) % N)) % N;
        float2 w1 = wtab[t1];
        ws[OFF_M1 + 2 * id] = w1.x;  ws[OFF_M1 + 2 * id + 1] = -w1.y;
        ws[OFF_M1T + 2 * (m * N + k)] = w1.x;  ws[OFF_M1T + 2 * (m * N + k) + 1] = -w1.y;
        int tw = (k * m) % N;
        float2 ww = wtab[tw];
        ws[OFF_WF + 2 * id] = ww.x;  ws[OFF_WF + 2 * id + 1] = -ww.y;
        int t2 = ((k + 84) * m) % N;
        float2 w2 = wtab[t2];
        ws[OFF_M2 + 2 * id] = w2.x * inv;  ws[OFF_M2 + 2 * id + 1] = w2.y * inv;
        ws[OFF_M2T + 2 * (m * N + k)] = w2.x * inv;  ws[OFF_M2T + 2 * (m * N + k) + 1] = w2.y * inv;
        if (k < CROP) {
            int t3 = ((k + 108) * ((m + 83) % N)) % N;
            float2 w3 = wtab[t3];
            ws[OFF_M3 + 2 * (k * N + m)] = w3.x * inv;  ws[OFF_M3 + 2 * (k * N + m) + 1] = w3.y * inv;
            if (m < HCOL) {
                ws[OFF_M3T84 + 2 * (m * CROP + k)] = w3.x * inv;
                ws[OFF_M3T84 + 2 * (m * CROP + k) + 1] = w3.y * inv;
            }
        }
        if (id < N) {
            float2 wp = wtab[(2 * id) % N];
            ws[OFF_PHI2 + 2 * id] = wp.x;
            ws[OFF_PHI2 + 2 * id + 1] = wp.y;
        }
    } else if (bx < 550) {
        int id = (bx - 109) * 256 + t;
        if (id >= 16 * MP * MP) return;
        int rc = id % (MP * MP);
        int r = rc / MP, c = rc % MP;
        float y = r - 41.5f, x = c - 41.5f;
        float2 v = {0.f, 0.f};
        if (x * x + y * y <= 1764.0f) {
            float sp, cp; sincosf(P[id], &sp, &cp);
            v.x = cp; v.y = sp;
        }
        ((float2*)(ws + OFF_PC))[id] = v;
    } else {
        __shared__ int red[256];
        int cnt = 0;
        for (int i = t; i < MP * MP; i += 256) {
            int r = i / MP, c = i % MP;
            float y = r - 41.5f, x = c - 41.5f;
            if (x * x + y * y <= 1764.0f) cnt++;
        }
        red[t] = cnt; __syncthreads();
        for (int s = 128; s > 0; s >>= 1) { if (t < s) red[t] += red[t + s]; __syncthreads(); }
        if (t == 0) ws[OFF_AMP] = (float)red[0];
    }
}

// ---------------- row transforms: T1 = M1 * xpad  |  T2 = F * Pc ----------------
__global__ __launch_bounds__(128) void k_rows(const float* __restrict__ x, float* ws) {
    int kr = blockIdx.x, bj = blockIdx.y, t = threadIdx.x;
    __shared__ float2 wbuf[NP];
    if (blockIdx.z == 0) {
        const float2* M1 = (const float2*)(ws + OFF_M1);
        if (t < NP) wbuf[t] = M1[kr * N + 39 + t];
        __syncthreads();
        if (t >= NP) return;
        float2 acc = {0.f, 0.f};
        for (int nr = 0; nr < NP; nr++) {
            float2 w = wbuf[nr];
            float xv = x[(bj * NP + nr) * NP + t];
            acc.x += w.x * xv; acc.y += w.y * xv;
        }
        ((float2*)(ws + OFF_T1))[(bj * N + kr) * NP + t] = acc;
    } else {
        const float2* WF = (const float2*)(ws + OFF_WF);
        if (t < MP) wbuf[t] = WF[kr * N + 42 + t];
        __syncthreads();
        if (t >= MP) return;
        const float2* PC = (const float2*)(ws + OFF_PC) + (size_t)bj * MP * MP;
        float2 acc = {0.f, 0.f};
        for (int nr = 0; nr < MP; nr++) {
            float2 w = wbuf[nr];
            float2 pc = PC[nr * MP + t];
            acc.x += w.x * pc.x - w.y * pc.y;
            acc.y += w.x * pc.y + w.y * pc.x;
        }
        ((float2*)(ws + OFF_T2))[(bj * N + kr) * MP + t] = acc;
    }
}

// ---------------- col transforms: X (Hermitian-halved) | A (full), b128 LDS reads ----------------
constexpr int RCH = 6;
__global__ __launch_bounds__(192) void k_cols(float* ws) {
    int bj = blockIdx.y, tid = threadIdx.x;
    __shared__ __align__(16) float2 sbuf[RCH * MP];   // 504 float2, covers both uses
    if (blockIdx.x < 84) {
        // ---- X[:,0..83] = T1 * M1^T, 2 rows/block ----
        int k0 = blockIdx.x * 2;
        const float2* T1 = (const float2*)(ws + OFF_T1);
        for (int idx = tid; idx < 2 * NP; idx += 192) {
            int r = idx / NP, m = idx % NP;
            if (k0 + r < N) sbuf[r * NP + m] = T1[((size_t)bj * N + k0 + r) * NP + m];
        }
        __syncthreads();
        int col = tid % HCOL, grp = tid / HCOL;
        if (grp >= 2) return;
        int kr = k0 + grp;
        if (kr >= N) return;
        const float2* M1T = (const float2*)(ws + OFF_M1T);
        float2 acc = {0.f, 0.f};
#pragma unroll 5
        for (int ncp = 0; ncp < 45; ncp++) {       // NP = 90 = 45 pairs
            int nc = 2 * ncp;
            float4 u = *(const float4*)&sbuf[grp * NP + nc];
            float2 w0 = M1T[(39 + nc) * N + col];
            float2 w1 = M1T[(40 + nc) * N + col];
            acc.x += u.x * w0.x - u.y * w0.y;
            acc.y += u.x * w0.y + u.y * w0.x;
            acc.x += u.z * w1.x - u.w * w1.y;
            acc.y += u.z * w1.y + u.w * w1.x;
        }
        ((float2*)(ws + OFF_X))[((size_t)bj * N + kr) * HCOL + col] = acc;
    } else {
        // ---- A = T2 * F^T, 6 rows/block, full 167 cols ----
        int i0 = (blockIdx.x - 84) * RCH;
        const float2* T2 = (const float2*)(ws + OFF_T2);
        for (int idx = tid; idx < RCH * MP; idx += 192) {
            int q = idx / MP, nc = idx % MP, kr = i0 + q;
            if (kr < N) sbuf[idx] = T2[(bj * N + kr) * MP + nc];
        }
        __syncthreads();
        if (tid >= N) return;
        const float2* WF = (const float2*)(ws + OFF_WF);
        float2 acc[RCH];
#pragma unroll
        for (int q = 0; q < RCH; q++) acc[q] = make_float2(0.f, 0.f);
        for (int ncp = 0; ncp < 42; ncp++) {       // MP = 84 = 42 pairs
            int nc = 2 * ncp;
            float2 w0 = WF[(42 + nc) * N + tid];
            float2 w1 = WF[(43 + nc) * N + tid];
#pragma unroll
            for (int q = 0; q < RCH; q++) {
                float4 u = *(const float4*)&sbuf[q * MP + nc];
                acc[q].x += u.x * w0.x - u.y * w0.y;
                acc[q].y += u.x * w0.y + u.y * w0.x;
                acc[q].x += u.z * w1.x - u.w * w1.y;
                acc[q].y += u.z * w1.y + u.w * w1.x;
            }
        }
        float2* A = (float2*)(ws + OFF_A);
#pragma unroll
        for (int q = 0; q < RCH; q++)
            if (i0 + q < N) A[((size_t)bj * N + i0 + q) * N + tid] = acc[q];
    }
}

// ---------------- stage 2c: T3[k, 0..83] = sum_m Bd[k,m] * M2T[m,t], Bd inline ----------------
__global__ __launch_bounds__(192) void k2c(float* ws) {
    int chunk = blockIdx.x, c = blockIdx.y, tid = threadIdx.x;
    int k0 = chunk * 2;
    __shared__ float bds[2][N];
    const float2* A = (const float2*)(ws + OFF_A);
    float inv_amp = 1.0f / ws[OFF_AMP];
    for (int idx = tid; idx < 2 * N; idx += 192) {
        int r = idx / N, m = idx % N;
        int k = k0 + r;
        if (k < N) {
            float2 a0 = A[((size_t)c * N + k) * N + m];
            float2 a1 = A[((size_t)(c + 8) * N + k) * N + m];
            bds[r][m] = (a0.x * a0.x + a0.y * a0.y - a1.x * a1.x - a1.y * a1.y) * inv_amp;
        }
    }
    __syncthreads();
    int col = tid % HCOL, grp = tid / HCOL;
    if (grp >= 2) return;
    int k = k0 + grp;
    if (k >= N) return;
    const float2* M2T = (const float2*)(ws + OFF_M2T);
    float2 acc = {0.f, 0.f};
    for (int m = 0; m < N; m++) {
        float bv = bds[grp][m];
        float2 w = M2T[m * N + col];
        acc.x += w.x * bv; acc.y += w.y * bv;
    }
    ((float2*)(ws + OFF_T3))[((size_t)c * N + k) * HCOL + col] = acc;
}

// ---------------- stage 2d: OTF[i, 0..83] = sum_k M2[i,k] * T3[k,t] ----------------
__global__ __launch_bounds__(192) void k2d(float* ws) {
    int chunk = blockIdx.x, c = blockIdx.y, tid = threadIdx.x;
    int i0 = chunk * 2;
    __shared__ float2 m2s[2][N];
    const float2* M2 = (const float2*)(ws + OFF_M2);
    for (int idx = tid; idx < 2 * N; idx += 192) {
        int r = idx / N, k = idx % N;
        if (i0 + r < N) m2s[r][k] = M2[(i0 + r) * N + k];
    }
    __syncthreads();
    int col = tid % HCOL, grp = tid / HCOL;
    if (grp >= 2) return;
    int i = i0 + grp;
    if (i >= N) return;
    const float2* T3 = (const float2*)(ws + OFF_T3) + (size_t)c * N * HCOL;
    float2 acc = {0.f, 0.f};
    for (int k = 0; k < N; k++) {
        float2 w = m2s[grp][k];
        float2 u = T3[k * HCOL + col];
        acc.x += u.x * w.x - u.y * w.y;
        acc.y += u.x * w.y + u.y * w.x;
    }
    ((float2*)(ws + OFF_OTF))[((size_t)c * N + i) * HCOL + col] = acc;
}

// ---------------- stage 3 fused: 12 rows/block, dbuf, float4 staging, VGPR-capped ----------------
constexpr int K34R = 12;   // rows per block (4 pool rows)
constexpr int KCH  = 16;   // kr chunk staged per iteration
constexpr int NT34 = (N + KCH - 1) / KCH;   // 11 (10 full + 1 tail of 7)

constexpr int SM_ZS   = 0;
constexpr int SM_M3C  = SM_ZS + 2 * KCH * HCOL * 2;      // 5376
constexpr int SM_PHIS = SM_M3C + 2 * KCH * K34R * 2;     // 6144
constexpr int SM_PM   = SM_PHIS + N * 2;                 // 6478
constexpr int SM_TOT  = SM_PM + 4 * CROP;                // 6958 floats = 27832 B

constexpr int ZBUF = KCH * HCOL;    // float2 elements per zs buffer
constexpr int MBUF = KCH * K34R;    // float2 elements per m3c buffer

#define K34_FMA_BODY(kl)                                                        \
    {                                                                           \
        float4 zz = *(const float4*)&zcur[(kl) * HCOL + 2 * pair];              \
        float4 wa = *(const float4*)&mcur[(kl) * K34R + r0];                    \
        a00.x += wa.x * zz.x - wa.y * zz.y;  a00.y += wa.x * zz.y + wa.y * zz.x;\
        a01.x += wa.x * zz.z - wa.y * zz.w;  a01.y += wa.x * zz.w + wa.y * zz.z;\
        a10.x += wa.z * zz.x - wa.w * zz.y;  a10.y += wa.z * zz.y + wa.w * zz.x;\
        a11.x += wa.z * zz.z - wa.w * zz.w;  a11.y += wa.z * zz.w + wa.w * zz.z;\
    }

__global__ __launch_bounds__(256, 8) void k34(float* ws) {
    int chunk = blockIdx.x, c = blockIdx.y, b = blockIdx.z, tid = threadIdx.x;
    int i0 = chunk * K34R;
    __shared__ __align__(16) float smem[SM_TOT];
    float2* zbase = (float2*)(smem + SM_ZS);
    float2* mbase = (float2*)(smem + SM_M3C);
    float2* phis  = (float2*)(smem + SM_PHIS);
    float*  pmf   = smem + SM_PM;                            // pm[4][CROP] flat
    float2 (*us)[HCOL] = (float2 (*)[HCOL])(smem + SM_ZS);   // alias: zs dead after loop

    const float2* M3 = (const float2*)(ws + OFF_M3);
    const float4* X4   = (const float4*)(ws + OFF_X   + (size_t)b * N * HCOL * 2);
    const float4* OTF4 = (const float4*)(ws + OFF_OTF + (size_t)c * N * HCOL * 2);
    for (int idx = tid; idx < N; idx += 256) phis[idx] = ((const float2*)(ws + OFF_PHI2))[idx];

    // staging coords: float4 = 2 cols; 42 quads/row; 672 quads per full chunk, 3/thread
    int qkl[3], qcp[3];
#pragma unroll
    for (int e = 0; e < 3; e++) {
        int idx = tid + e * 256;
        qkl[e] = idx / 42; qcp[e] = idx - qkl[e] * 42;
    }
    int mkl = tid & 15, mr = tid >> 4;   // tid<192: m3c coords

    int pair = tid % 42, grp = tid / 42;   // grp<6: 2 rows x 2 cols per thread
    int r0 = grp * 2;
    float2 a00 = {0.f,0.f}, a01 = {0.f,0.f}, a10 = {0.f,0.f}, a11 = {0.f,0.f};

    float4 xq[3], oq[3];
    float2 m3r;

    // ---- prologue: load chunk 0, write LDS buf 0 ----
#pragma unroll
    for (int e = 0; e < 3; e++)
        if (qkl[e] < KCH) { xq[e] = X4[qkl[e] * 42 + qcp[e]]; oq[e] = OTF4[qkl[e] * 42 + qcp[e]]; }
    if (tid < 192) m3r = M3[(i0 + mr) * N + mkl];
#pragma unroll
    for (int e = 0; e < 3; e++)
        if (qkl[e] < KCH) {
            float4 z;
            z.x = xq[e].x * oq[e].x - xq[e].y * oq[e].y;
            z.y = xq[e].x * oq[e].y + xq[e].y * oq[e].x;
            z.z = xq[e].z * oq[e].z - xq[e].w * oq[e].w;
            z.w = xq[e].z * oq[e].w + xq[e].w * oq[e].z;
            *(float4*)&zbase[qkl[e] * HCOL + 2 * qcp[e]] = z;
        }
    if (tid < 192) mbase[mkl * K34R + mr] = m3r;
    __syncthreads();

    // ---- main loop: prefetch(t+1) -> FMA(t) on cbuf (nbuf writes interleave) -> barrier ----
    for (int t = 0; t < NT34; t++) {
        int cbuf = t & 1, nbuf = cbuf ^ 1;
        int kr0 = t * KCH;
        int chn = min(KCH, N - kr0);
        int nbase = kr0 + KCH;
        int nchn = (t + 1 < NT34) ? (N - nbase < KCH ? N - nbase : KCH) : 0;
        if (nchn > 0) {
#pragma unroll
            for (int e = 0; e < 3; e++)
                if (qkl[e] < nchn) { xq[e] = X4[(nbase + qkl[e]) * 42 + qcp[e]];
                                     oq[e] = OTF4[(nbase + qkl[e]) * 42 + qcp[e]]; }
            if (tid < 192 && mkl < nchn) m3r = M3[(i0 + mr) * N + nbase + mkl];
        }
        const float2* zcur = zbase + cbuf * ZBUF;
        const float2* mcur = mbase + cbuf * MBUF;
        if (grp < 6) {
            if (chn == KCH) {
#pragma unroll
                for (int kl = 0; kl < KCH; kl++) K34_FMA_BODY(kl)
            } else {
#pragma unroll
                for (int kl = 0; kl < KCH - 9; kl++) K34_FMA_BODY(kl)   // tail chn = 7
            }
        }
        if (nchn > 0) {
            float2* znxt = zbase + nbuf * ZBUF;
            float2* mnxt = mbase + nbuf * MBUF;
#pragma unroll
            for (int e = 0; e < 3; e++)
                if (qkl[e] < nchn) {
                    float4 z;
                    z.x = xq[e].x * oq[e].x - xq[e].y * oq[e].y;
                    z.y = xq[e].x * oq[e].y + xq[e].y * oq[e].x;
                    z.z = xq[e].z * oq[e].z - xq[e].w * oq[e].w;
                    z.w = xq[e].z * oq[e].w + xq[e].w * oq[e].z;
                    *(float4*)&znxt[qkl[e] * HCOL + 2 * qcp[e]] = z;
                }
            if (tid < 192 && mkl < nchn) mnxt[mkl * K34R + mr] = m3r;
        }
        __syncthreads();
    }

    // ---- write U rows (us aliases zs; all zs reads completed before last barrier) ----
    if (grp < 6) {
        *(float4*)&us[r0][2 * pair]     = make_float4(a00.x, a00.y, a01.x, a01.y);
        *(float4*)&us[r0 + 1][2 * pair] = make_float4(a10.x, a10.y, a11.x, a11.y);
    }
    __syncthreads();

    // ---- phase 2: j-transform + phase fixup + noise + relu + 3-row max ----
    if (tid < 240) {
        int grp2 = tid / CROP, j = tid % CROP;
        int rbase = grp2 * 6;
        const float2* M3T84 = (const float2*)(ws + OFF_M3T84);
        float2 A[6]; float Bq[6];
#pragma unroll
        for (int q = 0; q < 6; q++) A[q] = make_float2(0.f, 0.f);
#pragma unroll 4
        for (int ncp = 0; ncp < 41; ncp++) {
            int nc = 2 * ncp;
            float2 w0 = M3T84[nc * CROP + j];
            float2 w1 = M3T84[(nc + 1) * CROP + j];
#pragma unroll
            for (int q = 0; q < 6; q++) {
                float4 u = *(const float4*)&us[rbase + q][nc];
                A[q].x += u.x * w0.x - u.y * w0.y;
                A[q].y += u.x * w0.y + u.y * w0.x;
                A[q].x += u.z * w1.x - u.w * w1.y;
                A[q].y += u.z * w1.y + u.w * w1.x;
            }
        }
        {   // nc = 82 singleton
            float2 w = M3T84[82 * CROP + j];
#pragma unroll
            for (int q = 0; q < 6; q++) {
                float2 u = us[rbase + q][82];
                A[q].x += u.x * w.x - u.y * w.y;
                A[q].y += u.x * w.y + u.y * w.x;
            }
        }
        {   // B term: nc = 83 (self-paired column), real part only
            float2 w = M3T84[(HCOL - 1) * CROP + j];
#pragma unroll
            for (int q = 0; q < 6; q++) {
                float2 u = us[rbase + q][HCOL - 1];
                Bq[q] = u.x * w.x - u.y * w.y;
            }
        }
#pragma unroll
        for (int g = 0; g < 2; g++) {
            float vmax = 0.f;  // relu folded in
#pragma unroll
            for (int r = 0; r < 3; r++) {
                int q = g * 3 + r, i = i0 + rbase + q;
                int s = i + j + 49; if (s >= N) s -= N;   // (i+j+216) mod 167
                float2 ph = phis[s];
                float val = A[q].x * (1.0f + ph.x) - A[q].y * ph.y + Bq[q];
                unsigned idx = (((unsigned)b * N + (24 + i)) * N + (24 + j)) * 8u + c;
                val += 0.003f * noise_at(idx);
                vmax = fmaxf(vmax, val);
            }
            pmf[(grp2 * 2 + g) * CROP + j] = vmax;
        }
    }
    __syncthreads();
    if (tid < 160) {
        int pr = tid / 40, pc = tid % 40;
        float m = fmaxf(fmaxf(pmf[pr * CROP + 3 * pc], pmf[pr * CROP + 3 * pc + 1]),
                        pmf[pr * CROP + 3 * pc + 2]);
        int prow = chunk * 4 + pr;
        ws[OFF_FLAT + (size_t)b * 12800 + ((size_t)prow * 40 + pc) * 8 + c] = m;
    }
}

// ---------------- stage 4: dense(12800->10) + softmax ----------------
__global__ void k5(const float* __restrict__ W3, const float* __restrict__ b3,
                   const float* __restrict__ ws, float* __restrict__ out) {
    int b = blockIdx.x, t = threadIdx.x;
    __shared__ float red[256][10];
    float acc[10];
#pragma unroll
    for (int o = 0; o < 10; o++) acc[o] = 0.f;
    const float* fl = ws + OFF_FLAT + (size_t)b * 12800;
    for (int f = t; f < 12800; f += 256) {
        float v = fl[f];
#pragma unroll
        for (int o = 0; o < 10; o++) acc[o] = fmaf(v, W3[f * 10 + o], acc[o]);
    }
#pragma unroll
    for (int o = 0; o < 10; o++) red[t][o] = acc[o];
    __syncthreads();
    for (int s = 128; s > 0; s >>= 1) {
        if (t < s) {
#pragma unroll
            for (int o = 0; o < 10; o++) red[t][o] += red[t + s][o];
        }
        __syncthreads();
    }
    if (t == 0) {
        float lg[10], mx = -1e30f;
#pragma unroll
        for (int o = 0; o < 10; o++) { lg[o] = red[0][o] + b3[o]; mx = fmaxf(mx, lg[o]); }
        float sum = 0.f;
#pragma unroll
        for (int o = 0; o < 10; o++) { lg[o] = expf(lg[o] - mx); sum += lg[o]; }
#pragma unroll
        for (int o = 0; o < 10; o++) out[b * 10 + o] = lg[o] / sum;
    }
}

extern "C" void kernel_launch(void* const* d_in, const int* in_sizes, int n_in,
                              void* d_out, int out_size, void* d_ws, size_t ws_size,
                              hipStream_t stream) {
    const float* x  = (const float*)d_in[0];   // [16,90,90,1]
    const float* P  = (const float*)d_in[1];   // [16,84,84]
    const float* W3 = (const float*)d_in[2];   // [12800,10]
    const float* b3 = (const float*)d_in[3];   // [10]
    float* ws  = (float*)d_ws;
    float* out = (float*)d_out;                // [16,10]

    k_prep<<<551, 256, 0, stream>>>(P, ws);
    k_rows<<<dim3(N, 16, 2), 128, 0, stream>>>(x, ws);
    k_cols<<<dim3(84 + 28, 16), 192, 0, stream>>>(ws);
    k2c<<<dim3(84, 8), 192, 0, stream>>>(ws);
    k2d<<<dim3(84, 8), 192, 0, stream>>>(ws);
    k34<<<dim3(CROP / K34R, 8, 16), 256, 0, stream>>>(ws);
    k5<<<16, 256, 0, stream>>>(W3, b3, ws, out);
}